// Round 1
// baseline (6053.780 us; speedup 1.0000x reference)
//
#include <hip/hip_runtime.h>
#include <math.h>

#define NN 100000
#define NE 1600000
#define NG 256
#define D  32
static constexpr float BN_EPS = 1e-5f;

// ---------------- layer 1 scatter: agg2[dst] += x[src], d=2 ----------------
__global__ void scatter2_k(const float* __restrict__ x,
                           const int* __restrict__ src,
                           const int* __restrict__ dst,
                           float* __restrict__ agg) {
    int e = blockIdx.x * 256 + threadIdx.x;
    if (e >= NE) return;
    int s = src[e], d = dst[e];
    float2 v = *reinterpret_cast<const float2*>(x + 2 * (size_t)s);
    atomicAdd(&agg[2 * d + 0], v.x);
    atomicAdd(&agg[2 * d + 1], v.y);
}

// ---------------- layer 1 MLP (in dim 2) + BN stats ----------------
__global__ __launch_bounds__(64) void mlp1_k(
        const float* __restrict__ x, const float* __restrict__ agg,
        const float* __restrict__ w_in, const float* __restrict__ b_in,
        const float* __restrict__ w_out, const float* __restrict__ b_out,
        float* __restrict__ zout, float* __restrict__ stats) {
    __shared__ float lwi[64], lbi[32], lwo[1024], lbo[32];
    __shared__ float zl[64][33];
    int t = threadIdx.x; // 64 threads
    lwi[t] = w_in[t];
    if (t < 32) { lbi[t] = b_in[t]; lbo[t] = b_out[t]; }
    for (int i = t; i < 1024; i += 64) lwo[i] = w_out[i];
    __syncthreads();
    int node = blockIdx.x * 64 + t;
    if (node < NN) {
        float h0 = x[2 * node + 0] + agg[2 * node + 0];
        float h1 = x[2 * node + 1] + agg[2 * node + 1];
        float y[32];
        #pragma unroll
        for (int k = 0; k < 32; k++) {
            float a = lbi[k] + h0 * lwi[k] + h1 * lwi[32 + k];
            y[k] = a > 0.f ? a : 0.f;
        }
        float z[32];
        #pragma unroll 4
        for (int k = 0; k < 32; k++) {
            float a = lbo[k];
            #pragma unroll
            for (int c = 0; c < 32; c++) a += y[c] * lwo[c * 32 + k];
            z[k] = a > 0.f ? a : 0.f;
        }
        float4* zo = reinterpret_cast<float4*>(zout + (size_t)node * 32);
        #pragma unroll
        for (int k = 0; k < 8; k++)
            zo[k] = make_float4(z[4*k], z[4*k+1], z[4*k+2], z[4*k+3]);
        #pragma unroll
        for (int k = 0; k < 32; k++) zl[t][k] = z[k];
    } else {
        for (int k = 0; k < 32; k++) zl[t][k] = 0.f;
    }
    __syncthreads();
    if (t < 32) {
        float s = 0.f, sq = 0.f;
        for (int n = 0; n < 64; n++) { float v = zl[n][t]; s += v; sq += v * v; }
        atomicAdd(&stats[t], s);
        atomicAdd(&stats[32 + t], sq);
    }
}

// ---------------- BN finalize -> scale/shift ----------------
__global__ void bnfin_k(const float* __restrict__ stats,
                        const float* __restrict__ gamma,
                        const float* __restrict__ beta,
                        float* __restrict__ sc) {
    int c = threadIdx.x;
    if (c >= 32) return;
    float mean = stats[c] * (1.f / NN);
    float var  = stats[32 + c] * (1.f / NN) - mean * mean;
    float scale = gamma[c] * rsqrtf(var + BN_EPS);
    sc[c] = scale;
    sc[32 + c] = beta[c] - mean * scale;
}

// ---------------- heavy scatter: agg[dst] += bn(z[src]), d=32 ----------------
// 4 threads per edge, 8 channels each
__global__ __launch_bounds__(256) void scatter32_k(
        const float* __restrict__ z, const float* __restrict__ sc,
        const int* __restrict__ src, const int* __restrict__ dst,
        float* __restrict__ agg) {
    __shared__ float lsc[64];
    int t = threadIdx.x;
    if (t < 64) lsc[t] = sc[t];
    __syncthreads();
    int gid = blockIdx.x * 256 + t;
    int e = gid >> 2;
    if (e >= NE) return;
    int q = gid & 3;
    int s = src[e], d = dst[e];
    int c0 = q * 8;
    const float4* zp = reinterpret_cast<const float4*>(z + (size_t)s * 32 + c0);
    float4 v0 = zp[0], v1 = zp[1];
    float* ap = agg + (size_t)d * 32 + c0;
    atomicAdd(ap + 0, v0.x * lsc[c0+0] + lsc[32+c0+0]);
    atomicAdd(ap + 1, v0.y * lsc[c0+1] + lsc[32+c0+1]);
    atomicAdd(ap + 2, v0.z * lsc[c0+2] + lsc[32+c0+2]);
    atomicAdd(ap + 3, v0.w * lsc[c0+3] + lsc[32+c0+3]);
    atomicAdd(ap + 4, v1.x * lsc[c0+4] + lsc[32+c0+4]);
    atomicAdd(ap + 5, v1.y * lsc[c0+5] + lsc[32+c0+5]);
    atomicAdd(ap + 6, v1.z * lsc[c0+6] + lsc[32+c0+6]);
    atomicAdd(ap + 7, v1.w * lsc[c0+7] + lsc[32+c0+7]);
}

// ---------------- heavy MLP (in dim 32) + BN stats ----------------
// 256 threads = 32 nodes x 8 threads; thread owns 4 channels
__global__ __launch_bounds__(256) void mlp32_k(
        const float* __restrict__ zprev, const float* __restrict__ agg,
        const float* __restrict__ sc,
        const float* __restrict__ w_in, const float* __restrict__ b_in,
        const float* __restrict__ w_out, const float* __restrict__ b_out,
        float* __restrict__ zout, float* __restrict__ stats) {
    __shared__ float lwi[1024], lwo[1024], lbi[32], lbo[32], lsc[64];
    __shared__ float zin[32][33];
    __shared__ float yl[32][33];
    __shared__ float part[256][8];
    int t = threadIdx.x;
    int n = t >> 3, q = t & 7;
    for (int i = t; i < 1024; i += 256) { lwi[i] = w_in[i]; lwo[i] = w_out[i]; }
    if (t < 32) { lbi[t] = b_in[t]; lbo[t] = b_out[t]; }
    if (t < 64) lsc[t] = sc[t];
    __syncthreads();
    int node = blockIdx.x * 32 + n;   // grid is exactly NN/32 blocks
    int c0 = q * 4;
    float4 h = *reinterpret_cast<const float4*>(zprev + (size_t)node * 32 + c0);
    float4 a = *reinterpret_cast<const float4*>(agg + (size_t)node * 32 + c0);
    zin[n][c0+0] = h.x * lsc[c0+0] + lsc[32+c0+0] + a.x;
    zin[n][c0+1] = h.y * lsc[c0+1] + lsc[32+c0+1] + a.y;
    zin[n][c0+2] = h.z * lsc[c0+2] + lsc[32+c0+2] + a.z;
    zin[n][c0+3] = h.w * lsc[c0+3] + lsc[32+c0+3] + a.w;
    __syncthreads();
    float acc0 = lbi[c0+0], acc1 = lbi[c0+1], acc2 = lbi[c0+2], acc3 = lbi[c0+3];
    #pragma unroll
    for (int c = 0; c < 32; c++) {
        float zv = zin[n][c];
        acc0 += zv * lwi[c*32 + c0+0];
        acc1 += zv * lwi[c*32 + c0+1];
        acc2 += zv * lwi[c*32 + c0+2];
        acc3 += zv * lwi[c*32 + c0+3];
    }
    yl[n][c0+0] = acc0 > 0.f ? acc0 : 0.f;
    yl[n][c0+1] = acc1 > 0.f ? acc1 : 0.f;
    yl[n][c0+2] = acc2 > 0.f ? acc2 : 0.f;
    yl[n][c0+3] = acc3 > 0.f ? acc3 : 0.f;
    __syncthreads();
    float o0 = lbo[c0+0], o1 = lbo[c0+1], o2 = lbo[c0+2], o3 = lbo[c0+3];
    #pragma unroll
    for (int c = 0; c < 32; c++) {
        float yv = yl[n][c];
        o0 += yv * lwo[c*32 + c0+0];
        o1 += yv * lwo[c*32 + c0+1];
        o2 += yv * lwo[c*32 + c0+2];
        o3 += yv * lwo[c*32 + c0+3];
    }
    o0 = o0 > 0.f ? o0 : 0.f;
    o1 = o1 > 0.f ? o1 : 0.f;
    o2 = o2 > 0.f ? o2 : 0.f;
    o3 = o3 > 0.f ? o3 : 0.f;
    *reinterpret_cast<float4*>(zout + (size_t)node * 32 + c0) = make_float4(o0, o1, o2, o3);
    part[t][0] = o0; part[t][1] = o1; part[t][2] = o2; part[t][3] = o3;
    part[t][4] = o0*o0; part[t][5] = o1*o1; part[t][6] = o2*o2; part[t][7] = o3*o3;
    __syncthreads();
    if (t < 32) {
        int ch = t, qq = ch >> 2, j = ch & 3;
        float s = 0.f, sq2 = 0.f;
        for (int nn = 0; nn < 32; nn++) {
            s   += part[nn*8 + qq][j];
            sq2 += part[nn*8 + qq][4 + j];
        }
        atomicAdd(&stats[ch], s);
        atomicAdd(&stats[32 + ch], sq2);
    }
}

// ---------------- global add pool: g[batch[i]] += bn(z[i]) ----------------
__global__ __launch_bounds__(256) void pool_k(
        const float* __restrict__ z, const float* __restrict__ sc,
        const int* __restrict__ batch, float* __restrict__ g) {
    __shared__ float lsc[64];
    int t = threadIdx.x;
    if (t < 64) lsc[t] = sc[t];
    __syncthreads();
    int gid = blockIdx.x * 256 + t;
    int node = gid >> 3;
    if (node >= NN) return;
    int q = gid & 7;
    int b = batch[node];
    int c0 = q * 4;
    float4 v = *reinterpret_cast<const float4*>(z + (size_t)node * 32 + c0);
    float* gp = g + (size_t)b * 32 + c0;
    atomicAdd(gp + 0, v.x * lsc[c0+0] + lsc[32+c0+0]);
    atomicAdd(gp + 1, v.y * lsc[c0+1] + lsc[32+c0+1]);
    atomicAdd(gp + 2, v.z * lsc[c0+2] + lsc[32+c0+2]);
    atomicAdd(gp + 3, v.w * lsc[c0+3] + lsc[32+c0+3]);
}

// ---------------- head: fc1 -> relu -> fc2 -> log_softmax ----------------
__global__ __launch_bounds__(256) void head_k(
        const float* __restrict__ g,
        const float* __restrict__ fc1w, const float* __restrict__ fc1b,
        const float* __restrict__ fc2w, const float* __restrict__ fc2b,
        float* __restrict__ out) {
    __shared__ float lw1[1024], lb1[32], lw2[64], lb2[2];
    int t = threadIdx.x;
    for (int i = t; i < 1024; i += 256) lw1[i] = fc1w[i];
    if (t < 32) lb1[t] = fc1b[t];
    if (t < 64) lw2[t] = fc2w[t];
    if (t < 2) lb2[t] = fc2b[t];
    __syncthreads();
    // thread t handles graph t
    float gv[32];
    #pragma unroll
    for (int c = 0; c < 32; c++) gv[c] = g[(size_t)t * 32 + c];
    float o0 = lb2[0], o1 = lb2[1];
    #pragma unroll 4
    for (int k = 0; k < 32; k++) {
        float a = lb1[k];
        #pragma unroll
        for (int c = 0; c < 32; c++) a += gv[c] * lw1[c * 32 + k];
        a = a > 0.f ? a : 0.f;
        o0 += a * lw2[k * 2 + 0];
        o1 += a * lw2[k * 2 + 1];
    }
    float m = fmaxf(o0, o1);
    float lse = m + logf(expf(o0 - m) + expf(o1 - m));
    out[t * 2 + 0] = o0 - lse;
    out[t * 2 + 1] = o1 - lse;
}

extern "C" void kernel_launch(void* const* d_in, const int* in_sizes, int n_in,
                              void* d_out, int out_size, void* d_ws, size_t ws_size,
                              hipStream_t stream) {
    const float* x      = (const float*)d_in[0];
    const int*   ei     = (const int*)d_in[1];
    const int*   src    = ei;
    const int*   dst    = ei + NE;
    const int*   batch  = (const int*)d_in[2];
    const float* w1_in  = (const float*)d_in[3];
    const float* b1_in  = (const float*)d_in[4];
    const float* w1_out = (const float*)d_in[5];
    const float* b1_out = (const float*)d_in[6];
    const float* ws_in  = (const float*)d_in[7];
    const float* bs_in  = (const float*)d_in[8];
    const float* ws_out = (const float*)d_in[9];
    const float* bs_out = (const float*)d_in[10];
    const float* gamma  = (const float*)d_in[11];
    const float* beta   = (const float*)d_in[12];
    const float* fc1w   = (const float*)d_in[13];
    const float* fc1b   = (const float*)d_in[14];
    const float* fc2w   = (const float*)d_in[15];
    const float* fc2b   = (const float*)d_in[16];
    float* out = (float*)d_out;

    float* bufA  = (float*)d_ws;
    float* bufB  = bufA + (size_t)NN * 32;
    float* agg   = bufB + (size_t)NN * 32;
    float* stats = agg + (size_t)NN * 32;
    float* sc    = stats + 64;
    float* g     = sc + 64;

    // ---- layer 1 (input dim 2) ----
    hipMemsetAsync(agg, 0, (size_t)NN * 2 * sizeof(float), stream);
    scatter2_k<<<(NE + 255) / 256, 256, 0, stream>>>(x, src, dst, agg);
    hipMemsetAsync(stats, 0, 64 * sizeof(float), stream);
    mlp1_k<<<(NN + 63) / 64, 64, 0, stream>>>(x, agg, w1_in, b1_in, w1_out, b1_out, bufA, stats);
    bnfin_k<<<1, 32, 0, stream>>>(stats, gamma, beta, sc);

    // ---- layers 2..5 (input dim 32) ----
    const float* cur = bufA;
    float* nxt = bufB;
    for (int j = 0; j < 4; j++) {
        hipMemsetAsync(agg, 0, (size_t)NN * 32 * sizeof(float), stream);
        scatter32_k<<<NE * 4 / 256, 256, 0, stream>>>(cur, sc, src, dst, agg);
        hipMemsetAsync(stats, 0, 64 * sizeof(float), stream);
        mlp32_k<<<NN / 32, 256, 0, stream>>>(cur, agg, sc,
                                             ws_in + j * 1024, bs_in + j * 32,
                                             ws_out + j * 1024, bs_out + j * 32,
                                             nxt, stats);
        bnfin_k<<<1, 32, 0, stream>>>(stats, gamma + (j + 1) * 32, beta + (j + 1) * 32, sc);
        float* tmp = (float*)cur; cur = nxt; nxt = tmp;
    }

    // ---- pool + head ----
    hipMemsetAsync(g, 0, (size_t)NG * 32 * sizeof(float), stream);
    pool_k<<<NN * 8 / 256, 256, 0, stream>>>(cur, sc, batch, g);
    head_k<<<1, 256, 0, stream>>>(g, fc1w, fc1b, fc2w, fc2b, out);
}

// Round 2
// 853.422 us; speedup vs baseline: 7.0935x; 7.0935x over previous
//
#include <hip/hip_runtime.h>
#include <math.h>

#define NN 100000
#define NE 1600000
#define NG 256
#define NB_SCAN ((NN + 255) / 256)   // 391
static constexpr float BN_EPS = 1e-5f;

// ============================ CSR build ============================
__global__ __launch_bounds__(256) void hist_k(const int* __restrict__ dst,
                                              int* __restrict__ deg) {
    int e = blockIdx.x * 256 + threadIdx.x;
    if (e < NE) atomicAdd(&deg[dst[e]], 1);
}

__global__ __launch_bounds__(256) void scan_sum_k(const int* __restrict__ deg,
                                                  int* __restrict__ bsum) {
    __shared__ int s[256];
    int t = threadIdx.x;
    int i = blockIdx.x * 256 + t;
    s[t] = (i < NN) ? deg[i] : 0;
    __syncthreads();
    for (int off = 128; off > 0; off >>= 1) {
        if (t < off) s[t] += s[t + off];
        __syncthreads();
    }
    if (t == 0) bsum[blockIdx.x] = s[0];
}

__global__ __launch_bounds__(512) void scan_top_k(const int* __restrict__ bsum,
                                                  int* __restrict__ boff) {
    __shared__ int s[512];
    int t = threadIdx.x;
    int my = (t < NB_SCAN) ? bsum[t] : 0;
    s[t] = my;
    __syncthreads();
    for (int off = 1; off < 512; off <<= 1) {
        int v = (t >= off) ? s[t - off] : 0;
        __syncthreads();
        s[t] += v;
        __syncthreads();
    }
    if (t < NB_SCAN) boff[t] = s[t] - my;  // exclusive
}

__global__ __launch_bounds__(256) void scan_fin_k(const int* __restrict__ deg,
                                                  const int* __restrict__ boff,
                                                  int* __restrict__ rowptr,
                                                  int* __restrict__ cursor) {
    __shared__ int s[256];
    int t = threadIdx.x;
    int i = blockIdx.x * 256 + t;
    int v = (i < NN) ? deg[i] : 0;
    s[t] = v;
    __syncthreads();
    for (int off = 1; off < 256; off <<= 1) {
        int u = (t >= off) ? s[t - off] : 0;
        __syncthreads();
        s[t] += u;
        __syncthreads();
    }
    int excl = s[t] - v + boff[blockIdx.x];
    if (i < NN) { rowptr[i] = excl; cursor[i] = excl; }
    if (i == NN - 1) rowptr[NN] = excl + v;   // == NE
}

__global__ __launch_bounds__(256) void fill_k(const int* __restrict__ src,
                                              const int* __restrict__ dst,
                                              int* __restrict__ cursor,
                                              int* __restrict__ csr) {
    int e = blockIdx.x * 256 + threadIdx.x;
    if (e < NE) {
        int pos = atomicAdd(&cursor[dst[e]], 1);
        csr[pos] = src[e];
    }
}

// ============== layer 1: gather(d=2) + MLP 2->32->32 + stats ==============
__global__ __launch_bounds__(64) void gmlp1_k(
        const float* __restrict__ x,
        const int* __restrict__ rowptr, const int* __restrict__ csr,
        const float* __restrict__ w_in, const float* __restrict__ b_in,
        const float* __restrict__ w_out, const float* __restrict__ b_out,
        float* __restrict__ zout, float* __restrict__ stats) {
    __shared__ float lwi[64], lbi[32], lwo[1024], lbo[32];
    __shared__ float zl[64][33];
    int t = threadIdx.x;
    lwi[t] = w_in[t];
    if (t < 32) { lbi[t] = b_in[t]; lbo[t] = b_out[t]; }
    for (int i = t; i < 1024; i += 64) lwo[i] = w_out[i];
    __syncthreads();
    int node = blockIdx.x * 64 + t;
    if (node < NN) {
        float2 self = *reinterpret_cast<const float2*>(x + 2 * (size_t)node);
        float h0 = self.x, h1 = self.y;
        int rs = rowptr[node], re = rowptr[node + 1];
        for (int k = rs; k < re; k++) {
            int s = csr[k];
            float2 v = *reinterpret_cast<const float2*>(x + 2 * (size_t)s);
            h0 += v.x; h1 += v.y;
        }
        float y[32];
        #pragma unroll
        for (int k = 0; k < 32; k++) {
            float a = lbi[k] + h0 * lwi[k] + h1 * lwi[32 + k];
            y[k] = a > 0.f ? a : 0.f;
        }
        float z[32];
        #pragma unroll 4
        for (int k = 0; k < 32; k++) {
            float a = lbo[k];
            #pragma unroll
            for (int c = 0; c < 32; c++) a += y[c] * lwo[c * 32 + k];
            z[k] = a > 0.f ? a : 0.f;
        }
        float4* zo = reinterpret_cast<float4*>(zout + (size_t)node * 32);
        #pragma unroll
        for (int k = 0; k < 8; k++)
            zo[k] = make_float4(z[4*k], z[4*k+1], z[4*k+2], z[4*k+3]);
        #pragma unroll
        for (int k = 0; k < 32; k++) zl[t][k] = z[k];
    } else {
        for (int k = 0; k < 32; k++) zl[t][k] = 0.f;
    }
    __syncthreads();
    if (t < 32) {
        float s = 0.f, sq = 0.f;
        for (int n = 0; n < 64; n++) { float v = zl[n][t]; s += v; sq += v * v; }
        atomicAdd(&stats[t], s);
        atomicAdd(&stats[32 + t], sq);
    }
}

// ---------------- BN finalize -> scale/shift ----------------
__global__ void bnfin_k(const float* __restrict__ stats,
                        const float* __restrict__ gamma,
                        const float* __restrict__ beta,
                        float* __restrict__ sc) {
    int c = threadIdx.x;
    if (c >= 32) return;
    float mean = stats[c] * (1.f / NN);
    float var  = stats[32 + c] * (1.f / NN) - mean * mean;
    float scale = gamma[c] * rsqrtf(var + BN_EPS);
    sc[c] = scale;
    sc[32 + c] = beta[c] - mean * scale;
}

// ======= heavy layer: gather(d=32, BN-folded) + MLP 32->32->32 + stats =======
// 256 threads = 32 nodes x 8 lanes; lane owns 4 channels.
// zin = scale*(z[node] + sum_j z[j]) + (deg+1)*shift   (BN commutes with sum)
__global__ __launch_bounds__(256) void gmlp32_k(
        const float* __restrict__ z, const float* __restrict__ sc,
        const int* __restrict__ rowptr, const int* __restrict__ csr,
        const float* __restrict__ w_in, const float* __restrict__ b_in,
        const float* __restrict__ w_out, const float* __restrict__ b_out,
        float* __restrict__ zout, float* __restrict__ stats) {
    __shared__ float lwi[1024], lwo[1024], lbi[32], lbo[32], lsc[64];
    __shared__ float zin[32][33];
    __shared__ float yl[32][33];
    __shared__ float part[256][8];
    int t = threadIdx.x;
    int n = t >> 3, q = t & 7, c0 = q * 4;
    for (int i = t; i < 1024; i += 256) { lwi[i] = w_in[i]; lwo[i] = w_out[i]; }
    if (t < 32) { lbi[t] = b_in[t]; lbo[t] = b_out[t]; }
    if (t < 64) lsc[t] = sc[t];
    __syncthreads();
    int node = blockIdx.x * 32 + n;   // grid exactly NN/32 blocks
    int rs = rowptr[node], re = rowptr[node + 1];
    float4 acc = *reinterpret_cast<const float4*>(z + (size_t)node * 32 + c0); // self
    for (int k = rs; k < re; k++) {
        int s = csr[k];
        float4 v = *reinterpret_cast<const float4*>(z + (size_t)s * 32 + c0);
        acc.x += v.x; acc.y += v.y; acc.z += v.z; acc.w += v.w;
    }
    float cnt = (float)(re - rs + 1);
    zin[n][c0+0] = acc.x * lsc[c0+0] + cnt * lsc[32+c0+0];
    zin[n][c0+1] = acc.y * lsc[c0+1] + cnt * lsc[32+c0+1];
    zin[n][c0+2] = acc.z * lsc[c0+2] + cnt * lsc[32+c0+2];
    zin[n][c0+3] = acc.w * lsc[c0+3] + cnt * lsc[32+c0+3];
    __syncthreads();
    float acc0 = lbi[c0+0], acc1 = lbi[c0+1], acc2 = lbi[c0+2], acc3 = lbi[c0+3];
    #pragma unroll
    for (int c = 0; c < 32; c++) {
        float zv = zin[n][c];
        acc0 += zv * lwi[c*32 + c0+0];
        acc1 += zv * lwi[c*32 + c0+1];
        acc2 += zv * lwi[c*32 + c0+2];
        acc3 += zv * lwi[c*32 + c0+3];
    }
    yl[n][c0+0] = acc0 > 0.f ? acc0 : 0.f;
    yl[n][c0+1] = acc1 > 0.f ? acc1 : 0.f;
    yl[n][c0+2] = acc2 > 0.f ? acc2 : 0.f;
    yl[n][c0+3] = acc3 > 0.f ? acc3 : 0.f;
    __syncthreads();
    float o0 = lbo[c0+0], o1 = lbo[c0+1], o2 = lbo[c0+2], o3 = lbo[c0+3];
    #pragma unroll
    for (int c = 0; c < 32; c++) {
        float yv = yl[n][c];
        o0 += yv * lwo[c*32 + c0+0];
        o1 += yv * lwo[c*32 + c0+1];
        o2 += yv * lwo[c*32 + c0+2];
        o3 += yv * lwo[c*32 + c0+3];
    }
    o0 = o0 > 0.f ? o0 : 0.f;
    o1 = o1 > 0.f ? o1 : 0.f;
    o2 = o2 > 0.f ? o2 : 0.f;
    o3 = o3 > 0.f ? o3 : 0.f;
    *reinterpret_cast<float4*>(zout + (size_t)node * 32 + c0) = make_float4(o0, o1, o2, o3);
    part[t][0] = o0; part[t][1] = o1; part[t][2] = o2; part[t][3] = o3;
    part[t][4] = o0*o0; part[t][5] = o1*o1; part[t][6] = o2*o2; part[t][7] = o3*o3;
    __syncthreads();
    if (t < 32) {
        int ch = t, qq = ch >> 2, j = ch & 3;
        float s = 0.f, sq2 = 0.f;
        for (int nn = 0; nn < 32; nn++) {
            s   += part[nn*8 + qq][j];
            sq2 += part[nn*8 + qq][4 + j];
        }
        atomicAdd(&stats[ch], s);
        atomicAdd(&stats[32 + ch], sq2);
    }
}

// ====== pool: batch is SORTED -> one block per graph, binary search ======
__global__ __launch_bounds__(256) void pool_seg_k(
        const float* __restrict__ z, const float* __restrict__ sc,
        const int* __restrict__ batch, float* __restrict__ g) {
    __shared__ float lsc[64];
    __shared__ float part[32][33];
    int t = threadIdx.x, slot = t >> 3, q = t & 7, c0 = q * 4;
    int gr = blockIdx.x;
    if (t < 64) lsc[t] = sc[t];
    // lower_bound(batch, gr)
    int lo = 0, hi = NN;
    while (lo < hi) { int mid = (lo + hi) >> 1; if (batch[mid] < gr) lo = mid + 1; else hi = mid; }
    int start = lo;
    // lower_bound(batch, gr+1)
    hi = NN;
    while (lo < hi) { int mid = (lo + hi) >> 1; if (batch[mid] < gr + 1) lo = mid + 1; else hi = mid; }
    int end = lo;
    float a0 = 0.f, a1 = 0.f, a2 = 0.f, a3 = 0.f;
    for (int i = start + slot; i < end; i += 32) {
        float4 v = *reinterpret_cast<const float4*>(z + (size_t)i * 32 + c0);
        a0 += v.x; a1 += v.y; a2 += v.z; a3 += v.w;
    }
    part[slot][c0+0] = a0; part[slot][c0+1] = a1;
    part[slot][c0+2] = a2; part[slot][c0+3] = a3;
    __syncthreads();
    if (t < 32) {
        float s = 0.f;
        for (int sl = 0; sl < 32; sl++) s += part[sl][t];
        float cnt = (float)(end - start);
        g[(size_t)gr * 32 + t] = s * lsc[t] + cnt * lsc[32 + t];
    }
}

// ---------------- head: fc1 -> relu -> fc2 -> log_softmax ----------------
__global__ __launch_bounds__(256) void head_k(
        const float* __restrict__ g,
        const float* __restrict__ fc1w, const float* __restrict__ fc1b,
        const float* __restrict__ fc2w, const float* __restrict__ fc2b,
        float* __restrict__ out) {
    __shared__ float lw1[1024], lb1[32], lw2[64], lb2[2];
    int t = threadIdx.x;
    for (int i = t; i < 1024; i += 256) lw1[i] = fc1w[i];
    if (t < 32) lb1[t] = fc1b[t];
    if (t < 64) lw2[t] = fc2w[t];
    if (t < 2) lb2[t] = fc2b[t];
    __syncthreads();
    float gv[32];
    #pragma unroll
    for (int c = 0; c < 32; c++) gv[c] = g[(size_t)t * 32 + c];
    float o0 = lb2[0], o1 = lb2[1];
    #pragma unroll 4
    for (int k = 0; k < 32; k++) {
        float a = lb1[k];
        #pragma unroll
        for (int c = 0; c < 32; c++) a += gv[c] * lw1[c * 32 + k];
        a = a > 0.f ? a : 0.f;
        o0 += a * lw2[k * 2 + 0];
        o1 += a * lw2[k * 2 + 1];
    }
    float m = fmaxf(o0, o1);
    float lse = m + logf(expf(o0 - m) + expf(o1 - m));
    out[t * 2 + 0] = o0 - lse;
    out[t * 2 + 1] = o1 - lse;
}

extern "C" void kernel_launch(void* const* d_in, const int* in_sizes, int n_in,
                              void* d_out, int out_size, void* d_ws, size_t ws_size,
                              hipStream_t stream) {
    const float* x      = (const float*)d_in[0];
    const int*   ei     = (const int*)d_in[1];
    const int*   src    = ei;
    const int*   dst    = ei + NE;
    const int*   batch  = (const int*)d_in[2];
    const float* w1_in  = (const float*)d_in[3];
    const float* b1_in  = (const float*)d_in[4];
    const float* w1_out = (const float*)d_in[5];
    const float* b1_out = (const float*)d_in[6];
    const float* ws_in  = (const float*)d_in[7];
    const float* bs_in  = (const float*)d_in[8];
    const float* ws_out = (const float*)d_in[9];
    const float* bs_out = (const float*)d_in[10];
    const float* gamma  = (const float*)d_in[11];
    const float* beta   = (const float*)d_in[12];
    const float* fc1w   = (const float*)d_in[13];
    const float* fc1b   = (const float*)d_in[14];
    const float* fc2w   = (const float*)d_in[15];
    const float* fc2b   = (const float*)d_in[16];
    float* out = (float*)d_out;

    // ---- workspace layout ----
    float* bufA  = (float*)d_ws;                 // NN*32
    float* bufB  = bufA + (size_t)NN * 32;       // NN*32
    float* stats = bufB + (size_t)NN * 32;       // 64
    float* sc    = stats + 64;                   // 64
    float* g     = sc + 64;                      // NG*32
    int*   deg    = (int*)(g + (size_t)NG * 32); // NN
    int*   cursor = deg + NN;                    // NN
    int*   rowptr = cursor + NN;                 // NN+1
    int*   bsum   = rowptr + NN + 1;             // NB_SCAN
    int*   boff   = bsum + NB_SCAN;              // NB_SCAN
    int*   csr    = boff + NB_SCAN;              // NE

    // ---- CSR build (once per call) ----
    hipMemsetAsync(deg, 0, (size_t)NN * sizeof(int), stream);
    hist_k<<<(NE + 255) / 256, 256, 0, stream>>>(dst, deg);
    scan_sum_k<<<NB_SCAN, 256, 0, stream>>>(deg, bsum);
    scan_top_k<<<1, 512, 0, stream>>>(bsum, boff);
    scan_fin_k<<<NB_SCAN, 256, 0, stream>>>(deg, boff, rowptr, cursor);
    fill_k<<<(NE + 255) / 256, 256, 0, stream>>>(src, dst, cursor, csr);

    // ---- layer 1 (input dim 2) ----
    hipMemsetAsync(stats, 0, 64 * sizeof(float), stream);
    gmlp1_k<<<(NN + 63) / 64, 64, 0, stream>>>(x, rowptr, csr,
                                               w1_in, b1_in, w1_out, b1_out, bufA, stats);
    bnfin_k<<<1, 32, 0, stream>>>(stats, gamma, beta, sc);

    // ---- layers 2..5 (input dim 32) ----
    const float* cur = bufA;
    float* nxt = bufB;
    for (int j = 0; j < 4; j++) {
        hipMemsetAsync(stats, 0, 64 * sizeof(float), stream);
        gmlp32_k<<<NN / 32, 256, 0, stream>>>(cur, sc, rowptr, csr,
                                              ws_in + j * 1024, bs_in + j * 32,
                                              ws_out + j * 1024, bs_out + j * 32,
                                              nxt, stats);
        bnfin_k<<<1, 32, 0, stream>>>(stats, gamma + (j + 1) * 32, beta + (j + 1) * 32, sc);
        float* tmp = (float*)cur; cur = nxt; nxt = tmp;
    }

    // ---- pool + head ----
    pool_seg_k<<<NG, 256, 0, stream>>>(cur, sc, batch, g);
    head_k<<<1, 256, 0, stream>>>(g, fc1w, fc1b, fc2w, fc2b, out);
}

// Round 5
// 687.279 us; speedup vs baseline: 8.8083x; 1.2417x over previous
//
#include <hip/hip_runtime.h>
#include <math.h>

#define NN 100000
#define NE 1600000
#define NG 256
#define NB_SCAN ((NN + 255) / 256)   // 391
static constexpr float BN_EPS = 1e-5f;

// ---- fp16 helpers (HW RNE via v_cvt) ----
__device__ inline float h2f(unsigned short u) {
    _Float16 h; __builtin_memcpy(&h, &u, 2); return (float)h;
}
__device__ inline unsigned short f2h(float f) {
    _Float16 h = (_Float16)f; unsigned short u; __builtin_memcpy(&u, &h, 2); return u;
}
__device__ inline unsigned int pack2(float a, float b) {
    return (unsigned int)f2h(a) | ((unsigned int)f2h(b) << 16);
}

// ============================ CSR build ============================
__global__ __launch_bounds__(256) void hist_k(const int* __restrict__ dst,
                                              int* __restrict__ deg) {
    int e = blockIdx.x * 256 + threadIdx.x;
    if (e < NE) atomicAdd(&deg[dst[e]], 1);
}

__global__ __launch_bounds__(256) void scan_sum_k(const int* __restrict__ deg,
                                                  int* __restrict__ bsum) {
    __shared__ int s[256];
    int t = threadIdx.x;
    int i = blockIdx.x * 256 + t;
    s[t] = (i < NN) ? deg[i] : 0;
    __syncthreads();
    for (int off = 128; off > 0; off >>= 1) {
        if (t < off) s[t] += s[t + off];
        __syncthreads();
    }
    if (t == 0) bsum[blockIdx.x] = s[0];
}

__global__ __launch_bounds__(512) void scan_top_k(const int* __restrict__ bsum,
                                                  int* __restrict__ boff) {
    __shared__ int s[512];
    int t = threadIdx.x;
    int my = (t < NB_SCAN) ? bsum[t] : 0;
    s[t] = my;
    __syncthreads();
    for (int off = 1; off < 512; off <<= 1) {
        int v = (t >= off) ? s[t - off] : 0;
        __syncthreads();
        s[t] += v;
        __syncthreads();
    }
    if (t < NB_SCAN) boff[t] = s[t] - my;  // exclusive
}

__global__ __launch_bounds__(256) void scan_fin_k(const int* __restrict__ deg,
                                                  const int* __restrict__ boff,
                                                  int* __restrict__ rowptr,
                                                  int* __restrict__ cursor) {
    __shared__ int s[256];
    int t = threadIdx.x;
    int i = blockIdx.x * 256 + t;
    int v = (i < NN) ? deg[i] : 0;
    s[t] = v;
    __syncthreads();
    for (int off = 1; off < 256; off <<= 1) {
        int u = (t >= off) ? s[t - off] : 0;
        __syncthreads();
        s[t] += u;
        __syncthreads();
    }
    int excl = s[t] - v + boff[blockIdx.x];
    if (i < NN) { rowptr[i] = excl; cursor[i] = excl; }
    if (i == NN - 1) rowptr[NN] = excl + v;   // == NE
}

__global__ __launch_bounds__(256) void fill_k(const int* __restrict__ src,
                                              const int* __restrict__ dst,
                                              int* __restrict__ cursor,
                                              int* __restrict__ csr) {
    int e = blockIdx.x * 256 + threadIdx.x;
    if (e < NE) {
        int pos = atomicAdd(&cursor[dst[e]], 1);
        csr[pos] = src[e];
    }
}

// ============== layer 1: gather(d=2) + MLP 2->32->32 + stats; out fp16 ======
__global__ __launch_bounds__(64) void gmlp1_k(
        const float* __restrict__ x,
        const int* __restrict__ rowptr, const int* __restrict__ csr,
        const float* __restrict__ w_in, const float* __restrict__ b_in,
        const float* __restrict__ w_out, const float* __restrict__ b_out,
        unsigned short* __restrict__ zout, float* __restrict__ stats) {
    __shared__ float lwi[64], lbi[32], lwo[1024], lbo[32];
    __shared__ float zl[64][33];
    int t = threadIdx.x;
    lwi[t] = w_in[t];
    if (t < 32) { lbi[t] = b_in[t]; lbo[t] = b_out[t]; }
    for (int i = t; i < 1024; i += 64) lwo[i] = w_out[i];
    __syncthreads();
    int node = blockIdx.x * 64 + t;
    if (node < NN) {
        float2 self = *reinterpret_cast<const float2*>(x + 2 * (size_t)node);
        float h0 = self.x, h1 = self.y;
        int rs = rowptr[node], re = rowptr[node + 1];
        for (int k = rs; k < re; k++) {
            int s = csr[k];
            float2 v = *reinterpret_cast<const float2*>(x + 2 * (size_t)s);
            h0 += v.x; h1 += v.y;
        }
        float y[32];
        #pragma unroll
        for (int k = 0; k < 32; k++) {
            float a = lbi[k] + h0 * lwi[k] + h1 * lwi[32 + k];
            y[k] = a > 0.f ? a : 0.f;
        }
        float z[32];
        #pragma unroll 4
        for (int k = 0; k < 32; k++) {
            float a = lbo[k];
            #pragma unroll
            for (int c = 0; c < 32; c++) a += y[c] * lwo[c * 32 + k];
            z[k] = a > 0.f ? a : 0.f;
        }
        uint4* zo = reinterpret_cast<uint4*>(zout + (size_t)node * 32);
        #pragma unroll
        for (int k = 0; k < 4; k++) {
            uint4 w;
            w.x = pack2(z[8*k+0], z[8*k+1]);
            w.y = pack2(z[8*k+2], z[8*k+3]);
            w.z = pack2(z[8*k+4], z[8*k+5]);
            w.w = pack2(z[8*k+6], z[8*k+7]);
            zo[k] = w;
        }
        #pragma unroll
        for (int k = 0; k < 32; k++) zl[t][k] = z[k];
    } else {
        for (int k = 0; k < 32; k++) zl[t][k] = 0.f;
    }
    __syncthreads();
    if (t < 32) {
        float s = 0.f, sq = 0.f;
        for (int n = 0; n < 64; n++) { float v = zl[n][t]; s += v; sq += v * v; }
        atomicAdd(&stats[t], s);
        atomicAdd(&stats[32 + t], sq);
    }
}

// ------- BN finalize -> scale/shift; also re-zeroes stats for next layer -----
__global__ void bnfin_k(float* __restrict__ stats,
                        const float* __restrict__ gamma,
                        const float* __restrict__ beta,
                        float* __restrict__ sc) {
    int c = threadIdx.x;
    if (c >= 32) return;
    float mean = stats[c] * (1.f / NN);
    float var  = stats[32 + c] * (1.f / NN) - mean * mean;
    float scale = gamma[c] * rsqrtf(var + BN_EPS);
    sc[c] = scale;
    sc[32 + c] = beta[c] - mean * scale;
    stats[c] = 0.f;
    stats[32 + c] = 0.f;
}

// ======= heavy layer: gather(fp16, BN-folded) + MLP 32->32->32 + stats =======
// 256 threads = 32 nodes x 8 lanes; lane owns 4 channels.
// zin = scale*(z[node] + sum_j z[j]) + (deg+1)*shift   (BN commutes with sum)
__global__ __launch_bounds__(256) void gmlp32_k(
        const unsigned short* __restrict__ z, const float* __restrict__ sc,
        const int* __restrict__ rowptr, const int* __restrict__ csr,
        const float* __restrict__ w_in, const float* __restrict__ b_in,
        const float* __restrict__ w_out, const float* __restrict__ b_out,
        unsigned short* __restrict__ zout, float* __restrict__ stats) {
    __shared__ float lwi[1024], lwo[1024], lbi[32], lbo[32], lsc[64];
    __shared__ float zin[32][33];
    __shared__ float yl[32][33];
    __shared__ float part[256][8];
    int t = threadIdx.x;
    int n = t >> 3, q = t & 7, c0 = q * 4;
    for (int i = t; i < 1024; i += 256) { lwi[i] = w_in[i]; lwo[i] = w_out[i]; }
    if (t < 32) { lbi[t] = b_in[t]; lbo[t] = b_out[t]; }
    if (t < 64) lsc[t] = sc[t];
    __syncthreads();
    int node = blockIdx.x * 32 + n;   // grid exactly NN/32 blocks
    int rs = rowptr[node], re = rowptr[node + 1];
    ushort4 sv = *reinterpret_cast<const ushort4*>(z + (size_t)node * 32 + c0);
    float a0 = h2f(sv.x), a1 = h2f(sv.y), a2 = h2f(sv.z), a3 = h2f(sv.w);
    for (int k = rs; k < re; k++) {
        int s = csr[k];
        ushort4 v = *reinterpret_cast<const ushort4*>(z + (size_t)s * 32 + c0);
        a0 += h2f(v.x); a1 += h2f(v.y); a2 += h2f(v.z); a3 += h2f(v.w);
    }
    float cnt = (float)(re - rs + 1);
    zin[n][c0+0] = a0 * lsc[c0+0] + cnt * lsc[32+c0+0];
    zin[n][c0+1] = a1 * lsc[c0+1] + cnt * lsc[32+c0+1];
    zin[n][c0+2] = a2 * lsc[c0+2] + cnt * lsc[32+c0+2];
    zin[n][c0+3] = a3 * lsc[c0+3] + cnt * lsc[32+c0+3];
    __syncthreads();
    float acc0 = lbi[c0+0], acc1 = lbi[c0+1], acc2 = lbi[c0+2], acc3 = lbi[c0+3];
    #pragma unroll
    for (int c = 0; c < 32; c++) {
        float zv = zin[n][c];
        acc0 += zv * lwi[c*32 + c0+0];
        acc1 += zv * lwi[c*32 + c0+1];
        acc2 += zv * lwi[c*32 + c0+2];
        acc3 += zv * lwi[c*32 + c0+3];
    }
    yl[n][c0+0] = acc0 > 0.f ? acc0 : 0.f;
    yl[n][c0+1] = acc1 > 0.f ? acc1 : 0.f;
    yl[n][c0+2] = acc2 > 0.f ? acc2 : 0.f;
    yl[n][c0+3] = acc3 > 0.f ? acc3 : 0.f;
    __syncthreads();
    float o0 = lbo[c0+0], o1 = lbo[c0+1], o2 = lbo[c0+2], o3 = lbo[c0+3];
    #pragma unroll
    for (int c = 0; c < 32; c++) {
        float yv = yl[n][c];
        o0 += yv * lwo[c*32 + c0+0];
        o1 += yv * lwo[c*32 + c0+1];
        o2 += yv * lwo[c*32 + c0+2];
        o3 += yv * lwo[c*32 + c0+3];
    }
    o0 = o0 > 0.f ? o0 : 0.f;
    o1 = o1 > 0.f ? o1 : 0.f;
    o2 = o2 > 0.f ? o2 : 0.f;
    o3 = o3 > 0.f ? o3 : 0.f;
    uint2 wout;
    wout.x = pack2(o0, o1);
    wout.y = pack2(o2, o3);
    *reinterpret_cast<uint2*>(zout + (size_t)node * 32 + c0) = wout;
    part[t][0] = o0; part[t][1] = o1; part[t][2] = o2; part[t][3] = o3;
    part[t][4] = o0*o0; part[t][5] = o1*o1; part[t][6] = o2*o2; part[t][7] = o3*o3;
    __syncthreads();
    if (t < 32) {
        int ch = t, qq = ch >> 2, j = ch & 3;
        float s = 0.f, sq2 = 0.f;
        for (int nn = 0; nn < 32; nn++) {
            s   += part[nn*8 + qq][j];
            sq2 += part[nn*8 + qq][4 + j];
        }
        atomicAdd(&stats[ch], s);
        atomicAdd(&stats[32 + ch], sq2);
    }
}

// ====== pool: batch is SORTED -> one block per graph, binary search ======
__global__ __launch_bounds__(256) void pool_seg_k(
        const unsigned short* __restrict__ z, const float* __restrict__ sc,
        const int* __restrict__ batch, float* __restrict__ g) {
    __shared__ float lsc[64];
    __shared__ float part[32][33];
    int t = threadIdx.x, slot = t >> 3, q = t & 7, c0 = q * 4;
    int gr = blockIdx.x;
    if (t < 64) lsc[t] = sc[t];
    int lo = 0, hi = NN;
    while (lo < hi) { int mid = (lo + hi) >> 1; if (batch[mid] < gr) lo = mid + 1; else hi = mid; }
    int start = lo;
    hi = NN;
    while (lo < hi) { int mid = (lo + hi) >> 1; if (batch[mid] < gr + 1) lo = mid + 1; else hi = mid; }
    int end = lo;
    float a0 = 0.f, a1 = 0.f, a2 = 0.f, a3 = 0.f;
    for (int i = start + slot; i < end; i += 32) {
        ushort4 v = *reinterpret_cast<const ushort4*>(z + (size_t)i * 32 + c0);
        a0 += h2f(v.x); a1 += h2f(v.y); a2 += h2f(v.z); a3 += h2f(v.w);
    }
    part[slot][c0+0] = a0; part[slot][c0+1] = a1;
    part[slot][c0+2] = a2; part[slot][c0+3] = a3;
    __syncthreads();
    if (t < 32) {
        float s = 0.f;
        for (int sl = 0; sl < 32; sl++) s += part[sl][t];
        float cnt = (float)(end - start);
        g[(size_t)gr * 32 + t] = s * lsc[t] + cnt * lsc[32 + t];
    }
}

// ---------------- head: fc1 -> relu -> fc2 -> log_softmax ----------------
__global__ __launch_bounds__(256) void head_k(
        const float* __restrict__ g,
        const float* __restrict__ fc1w, const float* __restrict__ fc1b,
        const float* __restrict__ fc2w, const float* __restrict__ fc2b,
        float* __restrict__ out) {
    __shared__ float lw1[1024], lb1[32], lw2[64], lb2[2];
    int t = threadIdx.x;
    for (int i = t; i < 1024; i += 256) lw1[i] = fc1w[i];
    if (t < 32) lb1[t] = fc1b[t];
    if (t < 64) lw2[t] = fc2w[t];
    if (t < 2) lb2[t] = fc2b[t];
    __syncthreads();
    float gv[32];
    #pragma unroll
    for (int c = 0; c < 32; c++) gv[c] = g[(size_t)t * 32 + c];
    float o0 = lb2[0], o1 = lb2[1];
    #pragma unroll 4
    for (int k = 0; k < 32; k++) {
        float a = lb1[k];
        #pragma unroll
        for (int c = 0; c < 32; c++) a += gv[c] * lw1[c * 32 + k];
        a = a > 0.f ? a : 0.f;
        o0 += a * lw2[k * 2 + 0];
        o1 += a * lw2[k * 2 + 1];
    }
    float m = fmaxf(o0, o1);
    float lse = m + logf(expf(o0 - m) + expf(o1 - m));
    out[t * 2 + 0] = o0 - lse;
    out[t * 2 + 1] = o1 - lse;
}

extern "C" void kernel_launch(void* const* d_in, const int* in_sizes, int n_in,
                              void* d_out, int out_size, void* d_ws, size_t ws_size,
                              hipStream_t stream) {
    const float* x      = (const float*)d_in[0];
    const int*   ei     = (const int*)d_in[1];
    const int*   src    = ei;
    const int*   dst    = ei + NE;
    const int*   batch  = (const int*)d_in[2];
    const float* w1_in  = (const float*)d_in[3];
    const float* b1_in  = (const float*)d_in[4];
    const float* w1_out = (const float*)d_in[5];
    const float* b1_out = (const float*)d_in[6];
    const float* ws_in  = (const float*)d_in[7];
    const float* bs_in  = (const float*)d_in[8];
    const float* ws_out = (const float*)d_in[9];
    const float* bs_out = (const float*)d_in[10];
    const float* gamma  = (const float*)d_in[11];
    const float* beta   = (const float*)d_in[12];
    const float* fc1w   = (const float*)d_in[13];
    const float* fc1b   = (const float*)d_in[14];
    const float* fc2w   = (const float*)d_in[15];
    const float* fc2b   = (const float*)d_in[16];
    float* out = (float*)d_out;

    // ---- workspace layout ----
    unsigned short* bufA = (unsigned short*)d_ws;        // NN*32 fp16
    unsigned short* bufB = bufA + (size_t)NN * 32;       // NN*32 fp16
    int*   deg    = (int*)(bufB + (size_t)NN * 32);      // NN
    float* stats  = (float*)(deg + NN);                  // 64  (adjacent to deg: one memset)
    float* sc     = stats + 64;                          // 64
    float* g      = sc + 64;                             // NG*32
    int*   cursor = (int*)(g + (size_t)NG * 32);         // NN
    int*   rowptr = cursor + NN;                         // NN+1
    int*   bsum   = rowptr + NN + 1;                     // NB_SCAN
    int*   boff   = bsum + NB_SCAN;                      // NB_SCAN
    int*   csr    = boff + NB_SCAN;                      // NE

    // ---- CSR build (once per call); zero deg + stats in one memset ----
    hipMemsetAsync(deg, 0, (size_t)(NN + 64) * sizeof(int), stream);
    hist_k<<<(NE + 255) / 256, 256, 0, stream>>>(dst, deg);
    scan_sum_k<<<NB_SCAN, 256, 0, stream>>>(deg, bsum);
    scan_top_k<<<1, 512, 0, stream>>>(bsum, boff);
    scan_fin_k<<<NB_SCAN, 256, 0, stream>>>(deg, boff, rowptr, cursor);
    fill_k<<<(NE + 255) / 256, 256, 0, stream>>>(src, dst, cursor, csr);

    // ---- layer 1 (input dim 2) ----
    gmlp1_k<<<(NN + 63) / 64, 64, 0, stream>>>(x, rowptr, csr,
                                               w1_in, b1_in, w1_out, b1_out, bufA, stats);
    bnfin_k<<<1, 32, 0, stream>>>(stats, gamma, beta, sc);

    // ---- layers 2..5 (input dim 32) ----
    const unsigned short* cur = bufA;
    unsigned short* nxt = bufB;
    for (int j = 0; j < 4; j++) {
        gmlp32_k<<<NN / 32, 256, 0, stream>>>(cur, sc, rowptr, csr,
                                              ws_in + j * 1024, bs_in + j * 32,
                                              ws_out + j * 1024, bs_out + j * 32,
                                              nxt, stats);
        bnfin_k<<<1, 32, 0, stream>>>(stats, gamma + (j + 1) * 32, beta + (j + 1) * 32, sc);
        unsigned short* tmp = (unsigned short*)cur; cur = nxt; nxt = tmp;
    }

    // ---- pool + head ----
    pool_seg_k<<<NG, 256, 0, stream>>>(cur, sc, batch, g);
    head_k<<<1, 256, 0, stream>>>(g, fc1w, fc1b, fc2w, fc2b, out);
}

// Round 7
// 563.777 us; speedup vs baseline: 10.7379x; 1.2191x over previous
//
#include <hip/hip_runtime.h>
#include <math.h>

#define NN 100000
#define NE 1600000
#define NG 256
#define NB_SCAN ((NN + 255) / 256)   // 391
#define NPART 8
#define PSZ (NN / NPART)             // 12500 exact
#define EPB 2048                     // edges per chunk
#define NCHUNK ((NE + EPB - 1) / EPB) // 782
static constexpr float BN_EPS = 1e-5f;

// ---- fp16 helpers (HW RNE via v_cvt) ----
__device__ inline float h2f(unsigned short u) {
    _Float16 h; __builtin_memcpy(&h, &u, 2); return (float)h;
}
__device__ inline unsigned short f2h(float f) {
    _Float16 h = (_Float16)f; unsigned short u; __builtin_memcpy(&u, &h, 2); return u;
}
__device__ inline unsigned int pack2(float a, float b) {
    return (unsigned int)f2h(a) | ((unsigned int)f2h(b) << 16);
}

// ============== CSR build: dst-range partitioned (XCD-local writes) ==========
__global__ __launch_bounds__(256) void hist_part_k(const int* __restrict__ dst,
                                                   int* __restrict__ deg) {
    int p = blockIdx.x & (NPART - 1);
    int chunk = blockIdx.x >> 3;
    int lo = p * PSZ;
    int base = chunk * EPB + threadIdx.x;
    #pragma unroll
    for (int i = 0; i < EPB / 256; i++) {
        int e = base + i * 256;
        if (e < NE) {
            int d = dst[e];
            if ((unsigned)(d - lo) < (unsigned)PSZ) atomicAdd(&deg[d], 1);
        }
    }
}

__global__ __launch_bounds__(256) void scan_sum_k(const int* __restrict__ deg,
                                                  int* __restrict__ bsum) {
    __shared__ int s[256];
    int t = threadIdx.x;
    int i = blockIdx.x * 256 + t;
    s[t] = (i < NN) ? deg[i] : 0;
    __syncthreads();
    for (int off = 128; off > 0; off >>= 1) {
        if (t < off) s[t] += s[t + off];
        __syncthreads();
    }
    if (t == 0) bsum[blockIdx.x] = s[0];
}

__global__ __launch_bounds__(512) void scan_top_k(const int* __restrict__ bsum,
                                                  int* __restrict__ boff) {
    __shared__ int s[512];
    int t = threadIdx.x;
    int my = (t < NB_SCAN) ? bsum[t] : 0;
    s[t] = my;
    __syncthreads();
    for (int off = 1; off < 512; off <<= 1) {
        int v = (t >= off) ? s[t - off] : 0;
        __syncthreads();
        s[t] += v;
        __syncthreads();
    }
    if (t < NB_SCAN) boff[t] = s[t] - my;  // exclusive
}

__global__ __launch_bounds__(256) void scan_fin_k(const int* __restrict__ deg,
                                                  const int* __restrict__ boff,
                                                  int* __restrict__ rowptr,
                                                  int* __restrict__ cursor) {
    __shared__ int s[256];
    int t = threadIdx.x;
    int i = blockIdx.x * 256 + t;
    int v = (i < NN) ? deg[i] : 0;
    s[t] = v;
    __syncthreads();
    for (int off = 1; off < 256; off <<= 1) {
        int u = (t >= off) ? s[t - off] : 0;
        __syncthreads();
        s[t] += u;
        __syncthreads();
    }
    int excl = s[t] - v + boff[blockIdx.x];
    if (i < NN) { rowptr[i] = excl; cursor[i] = excl; }
    if (i == NN - 1) rowptr[NN] = excl + v;   // == NE
}

__global__ __launch_bounds__(256) void fill_part_k(const int* __restrict__ src,
                                                   const int* __restrict__ dst,
                                                   int* __restrict__ cursor,
                                                   int* __restrict__ csr) {
    int p = blockIdx.x & (NPART - 1);
    int chunk = blockIdx.x >> 3;
    int lo = p * PSZ;
    int base = chunk * EPB + threadIdx.x;
    #pragma unroll
    for (int i = 0; i < EPB / 256; i++) {
        int e = base + i * 256;
        if (e < NE) {
            int d = dst[e];
            if ((unsigned)(d - lo) < (unsigned)PSZ) {
                int pos = atomicAdd(&cursor[d], 1);
                csr[pos] = src[e];
            }
        }
    }
}

// ============== layer 1: gather(d=2) + MLP 2->32->32 + stats0 ==============
__global__ __launch_bounds__(64) void gmlp1_k(
        const float* __restrict__ x,
        const int* __restrict__ rowptr, const int* __restrict__ csr,
        const float* __restrict__ w_in, const float* __restrict__ b_in,
        const float* __restrict__ w_out, const float* __restrict__ b_out,
        unsigned short* __restrict__ zout, float* __restrict__ stats) {
    __shared__ float lwi[64], lbi[32], lwo[1024], lbo[32];
    __shared__ float zl[64][33];
    int t = threadIdx.x;
    lwi[t] = w_in[t];
    if (t < 32) { lbi[t] = b_in[t]; lbo[t] = b_out[t]; }
    for (int i = t; i < 1024; i += 64) lwo[i] = w_out[i];
    __syncthreads();
    int node = blockIdx.x * 64 + t;
    if (node < NN) {
        float2 self = *reinterpret_cast<const float2*>(x + 2 * (size_t)node);
        float h0 = self.x, h1 = self.y;
        float g0 = 0.f, g1 = 0.f;
        int rs = rowptr[node], re = rowptr[node + 1];
        int k = rs;
        for (; k + 4 <= re; k += 4) {
            int s0 = csr[k], s1 = csr[k+1], s2 = csr[k+2], s3 = csr[k+3];
            float2 v0 = *reinterpret_cast<const float2*>(x + 2 * (size_t)s0);
            float2 v1 = *reinterpret_cast<const float2*>(x + 2 * (size_t)s1);
            float2 v2 = *reinterpret_cast<const float2*>(x + 2 * (size_t)s2);
            float2 v3 = *reinterpret_cast<const float2*>(x + 2 * (size_t)s3);
            h0 += v0.x + v2.x; h1 += v0.y + v2.y;
            g0 += v1.x + v3.x; g1 += v1.y + v3.y;
        }
        for (; k < re; k++) {
            int s = csr[k];
            float2 v = *reinterpret_cast<const float2*>(x + 2 * (size_t)s);
            h0 += v.x; h1 += v.y;
        }
        h0 += g0; h1 += g1;
        float y[32];
        #pragma unroll
        for (int kk = 0; kk < 32; kk++) {
            float a = lbi[kk] + h0 * lwi[kk] + h1 * lwi[32 + kk];
            y[kk] = a > 0.f ? a : 0.f;
        }
        float z[32];
        #pragma unroll 4
        for (int kk = 0; kk < 32; kk++) {
            float a = lbo[kk];
            #pragma unroll
            for (int c = 0; c < 32; c++) a += y[c] * lwo[c * 32 + kk];
            z[kk] = a > 0.f ? a : 0.f;
        }
        uint4* zo = reinterpret_cast<uint4*>(zout + (size_t)node * 32);
        #pragma unroll
        for (int kk = 0; kk < 4; kk++) {
            uint4 w;
            w.x = pack2(z[8*kk+0], z[8*kk+1]);
            w.y = pack2(z[8*kk+2], z[8*kk+3]);
            w.z = pack2(z[8*kk+4], z[8*kk+5]);
            w.w = pack2(z[8*kk+6], z[8*kk+7]);
            zo[kk] = w;
        }
        #pragma unroll
        for (int kk = 0; kk < 32; kk++) zl[t][kk] = z[kk];
    } else {
        for (int kk = 0; kk < 32; kk++) zl[t][kk] = 0.f;
    }
    __syncthreads();
    if (t < 32) {
        float s = 0.f, sq = 0.f;
        for (int n = 0; n < 64; n++) { float v = zl[n][t]; s += v; sq += v * v; }
        atomicAdd(&stats[t], s);
        atomicAdd(&stats[32 + t], sq);
    }
}

// ======= heavy layer: in-block BN + gather(fp16, x4 unroll) + MLP + stats ====
// 256 threads = 32 nodes x 8 lanes; lane owns 4 channels.
// zin = scale*(z[node] + sum_j z[j]) + (deg+1)*shift   (BN commutes with sum)
__global__ __launch_bounds__(256) void gmlp32_k(
        const unsigned short* __restrict__ z,
        const float* __restrict__ statsIn,
        const float* __restrict__ gamma, const float* __restrict__ beta,
        const int* __restrict__ rowptr, const int* __restrict__ csr,
        const float* __restrict__ w_in, const float* __restrict__ b_in,
        const float* __restrict__ w_out, const float* __restrict__ b_out,
        unsigned short* __restrict__ zout, float* __restrict__ statsOut) {
    __shared__ float lwi[1024], lwo[1024], lbi[32], lbo[32], lsc[64];
    __shared__ float zin[32][33];
    __shared__ float yl[32][33];
    __shared__ float part[256][8];
    int t = threadIdx.x;
    int n = t >> 3, q = t & 7, c0 = q * 4;
    for (int i = t; i < 1024; i += 256) { lwi[i] = w_in[i]; lwo[i] = w_out[i]; }
    if (t < 32) {
        lbi[t] = b_in[t]; lbo[t] = b_out[t];
        float mean = statsIn[t] * (1.f / NN);
        float var  = statsIn[32 + t] * (1.f / NN) - mean * mean;
        float scale = gamma[t] * rsqrtf(var + BN_EPS);
        lsc[t] = scale;
        lsc[32 + t] = beta[t] - mean * scale;
    }
    __syncthreads();
    int node = blockIdx.x * 32 + n;   // grid exactly NN/32 blocks
    int rs = rowptr[node], re = rowptr[node + 1];
    ushort4 sv = *reinterpret_cast<const ushort4*>(z + (size_t)node * 32 + c0);
    float a0 = h2f(sv.x), a1 = h2f(sv.y), a2 = h2f(sv.z), a3 = h2f(sv.w);
    float b0 = 0.f, b1 = 0.f, b2 = 0.f, b3 = 0.f;
    int k = rs;
    for (; k + 4 <= re; k += 4) {
        int s0 = csr[k], s1 = csr[k+1], s2 = csr[k+2], s3 = csr[k+3];
        ushort4 v0 = *reinterpret_cast<const ushort4*>(z + (size_t)s0 * 32 + c0);
        ushort4 v1 = *reinterpret_cast<const ushort4*>(z + (size_t)s1 * 32 + c0);
        ushort4 v2 = *reinterpret_cast<const ushort4*>(z + (size_t)s2 * 32 + c0);
        ushort4 v3 = *reinterpret_cast<const ushort4*>(z + (size_t)s3 * 32 + c0);
        a0 += h2f(v0.x) + h2f(v2.x); a1 += h2f(v0.y) + h2f(v2.y);
        a2 += h2f(v0.z) + h2f(v2.z); a3 += h2f(v0.w) + h2f(v2.w);
        b0 += h2f(v1.x) + h2f(v3.x); b1 += h2f(v1.y) + h2f(v3.y);
        b2 += h2f(v1.z) + h2f(v3.z); b3 += h2f(v1.w) + h2f(v3.w);
    }
    for (; k < re; k++) {
        int s = csr[k];
        ushort4 v = *reinterpret_cast<const ushort4*>(z + (size_t)s * 32 + c0);
        a0 += h2f(v.x); a1 += h2f(v.y); a2 += h2f(v.z); a3 += h2f(v.w);
    }
    a0 += b0; a1 += b1; a2 += b2; a3 += b3;
    float cnt = (float)(re - rs + 1);
    zin[n][c0+0] = a0 * lsc[c0+0] + cnt * lsc[32+c0+0];
    zin[n][c0+1] = a1 * lsc[c0+1] + cnt * lsc[32+c0+1];
    zin[n][c0+2] = a2 * lsc[c0+2] + cnt * lsc[32+c0+2];
    zin[n][c0+3] = a3 * lsc[c0+3] + cnt * lsc[32+c0+3];
    __syncthreads();
    float acc0 = lbi[c0+0], acc1 = lbi[c0+1], acc2 = lbi[c0+2], acc3 = lbi[c0+3];
    #pragma unroll
    for (int c = 0; c < 32; c++) {
        float zv = zin[n][c];
        acc0 += zv * lwi[c*32 + c0+0];
        acc1 += zv * lwi[c*32 + c0+1];
        acc2 += zv * lwi[c*32 + c0+2];
        acc3 += zv * lwi[c*32 + c0+3];
    }
    yl[n][c0+0] = acc0 > 0.f ? acc0 : 0.f;
    yl[n][c0+1] = acc1 > 0.f ? acc1 : 0.f;
    yl[n][c0+2] = acc2 > 0.f ? acc2 : 0.f;
    yl[n][c0+3] = acc3 > 0.f ? acc3 : 0.f;
    __syncthreads();
    float o0 = lbo[c0+0], o1 = lbo[c0+1], o2 = lbo[c0+2], o3 = lbo[c0+3];
    #pragma unroll
    for (int c = 0; c < 32; c++) {
        float yv = yl[n][c];
        o0 += yv * lwo[c*32 + c0+0];
        o1 += yv * lwo[c*32 + c0+1];
        o2 += yv * lwo[c*32 + c0+2];
        o3 += yv * lwo[c*32 + c0+3];
    }
    o0 = o0 > 0.f ? o0 : 0.f;
    o1 = o1 > 0.f ? o1 : 0.f;
    o2 = o2 > 0.f ? o2 : 0.f;
    o3 = o3 > 0.f ? o3 : 0.f;
    uint2 wout;
    wout.x = pack2(o0, o1);
    wout.y = pack2(o2, o3);
    *reinterpret_cast<uint2*>(zout + (size_t)node * 32 + c0) = wout;
    part[t][0] = o0; part[t][1] = o1; part[t][2] = o2; part[t][3] = o3;
    part[t][4] = o0*o0; part[t][5] = o1*o1; part[t][6] = o2*o2; part[t][7] = o3*o3;
    __syncthreads();
    if (t < 32) {
        int ch = t, qq = ch >> 2, j = ch & 3;
        float s = 0.f, sq2 = 0.f;
        for (int nn = 0; nn < 32; nn++) {
            s   += part[nn*8 + qq][j];
            sq2 += part[nn*8 + qq][4 + j];
        }
        atomicAdd(&statsOut[ch], s);
        atomicAdd(&statsOut[32 + ch], sq2);
    }
}

// ====== pool: batch is SORTED -> one block per graph, binary search ======
__global__ __launch_bounds__(256) void pool_seg_k(
        const unsigned short* __restrict__ z,
        const float* __restrict__ statsIn,
        const float* __restrict__ gamma, const float* __restrict__ beta,
        const int* __restrict__ batch, float* __restrict__ g) {
    __shared__ float lsc[64];
    __shared__ float part[32][33];
    int t = threadIdx.x, slot = t >> 3, q = t & 7, c0 = q * 4;
    int gr = blockIdx.x;
    if (t < 32) {
        float mean = statsIn[t] * (1.f / NN);
        float var  = statsIn[32 + t] * (1.f / NN) - mean * mean;
        float scale = gamma[t] * rsqrtf(var + BN_EPS);
        lsc[t] = scale;
        lsc[32 + t] = beta[t] - mean * scale;
    }
    int lo = 0, hi = NN;
    while (lo < hi) { int mid = (lo + hi) >> 1; if (batch[mid] < gr) lo = mid + 1; else hi = mid; }
    int start = lo;
    hi = NN;
    while (lo < hi) { int mid = (lo + hi) >> 1; if (batch[mid] < gr + 1) lo = mid + 1; else hi = mid; }
    int end = lo;
    float a0 = 0.f, a1 = 0.f, a2 = 0.f, a3 = 0.f;
    for (int i = start + slot; i < end; i += 32) {
        ushort4 v = *reinterpret_cast<const ushort4*>(z + (size_t)i * 32 + c0);
        a0 += h2f(v.x); a1 += h2f(v.y); a2 += h2f(v.z); a3 += h2f(v.w);
    }
    part[slot][c0+0] = a0; part[slot][c0+1] = a1;
    part[slot][c0+2] = a2; part[slot][c0+3] = a3;
    __syncthreads();
    if (t < 32) {
        float s = 0.f;
        for (int sl = 0; sl < 32; sl++) s += part[sl][t];
        float cnt = (float)(end - start);
        g[(size_t)gr * 32 + t] = s * lsc[t] + cnt * lsc[32 + t];
    }
}

// ---------------- head: fc1 -> relu -> fc2 -> log_softmax ----------------
__global__ __launch_bounds__(256) void head_k(
        const float* __restrict__ g,
        const float* __restrict__ fc1w, const float* __restrict__ fc1b,
        const float* __restrict__ fc2w, const float* __restrict__ fc2b,
        float* __restrict__ out) {
    __shared__ float lw1[1024], lb1[32], lw2[64], lb2[2];
    int t = threadIdx.x;
    for (int i = t; i < 1024; i += 256) lw1[i] = fc1w[i];
    if (t < 32) lb1[t] = fc1b[t];
    if (t < 64) lw2[t] = fc2w[t];
    if (t < 2) lb2[t] = fc2b[t];
    __syncthreads();
    float gv[32];
    #pragma unroll
    for (int c = 0; c < 32; c++) gv[c] = g[(size_t)t * 32 + c];
    float o0 = lb2[0], o1 = lb2[1];
    #pragma unroll 4
    for (int k = 0; k < 32; k++) {
        float a = lb1[k];
        #pragma unroll
        for (int c = 0; c < 32; c++) a += gv[c] * lw1[c * 32 + k];
        a = a > 0.f ? a : 0.f;
        o0 += a * lw2[k * 2 + 0];
        o1 += a * lw2[k * 2 + 1];
    }
    float m = fmaxf(o0, o1);
    float lse = m + logf(expf(o0 - m) + expf(o1 - m));
    out[t * 2 + 0] = o0 - lse;
    out[t * 2 + 1] = o1 - lse;
}

extern "C" void kernel_launch(void* const* d_in, const int* in_sizes, int n_in,
                              void* d_out, int out_size, void* d_ws, size_t ws_size,
                              hipStream_t stream) {
    const float* x      = (const float*)d_in[0];
    const int*   ei     = (const int*)d_in[1];
    const int*   src    = ei;
    const int*   dst    = ei + NE;
    const int*   batch  = (const int*)d_in[2];
    const float* w1_in  = (const float*)d_in[3];
    const float* b1_in  = (const float*)d_in[4];
    const float* w1_out = (const float*)d_in[5];
    const float* b1_out = (const float*)d_in[6];
    const float* ws_in  = (const float*)d_in[7];
    const float* bs_in  = (const float*)d_in[8];
    const float* ws_out = (const float*)d_in[9];
    const float* bs_out = (const float*)d_in[10];
    const float* gamma  = (const float*)d_in[11];
    const float* beta   = (const float*)d_in[12];
    const float* fc1w   = (const float*)d_in[13];
    const float* fc1b   = (const float*)d_in[14];
    const float* fc2w   = (const float*)d_in[15];
    const float* fc2b   = (const float*)d_in[16];
    float* out = (float*)d_out;

    // ---- workspace layout ----
    unsigned short* bufA = (unsigned short*)d_ws;        // NN*32 fp16
    unsigned short* bufB = bufA + (size_t)NN * 32;       // NN*32 fp16
    int*   deg    = (int*)(bufB + (size_t)NN * 32);      // NN
    float* stats  = (float*)(deg + NN);                  // 5 * 64 (adjacent: one memset)
    float* g      = stats + 5 * 64;                      // NG*32
    int*   cursor = (int*)(g + (size_t)NG * 32);         // NN
    int*   rowptr = cursor + NN;                         // NN+1
    int*   bsum   = rowptr + NN + 1;                     // NB_SCAN
    int*   boff   = bsum + NB_SCAN;                      // NB_SCAN
    int*   csr    = boff + NB_SCAN;                      // NE

    // ---- CSR build (partitioned); zero deg + all 5 stats slots in one memset
    hipMemsetAsync(deg, 0, (size_t)(NN + 5 * 64) * sizeof(int), stream);
    hist_part_k<<<NCHUNK * NPART, 256, 0, stream>>>(dst, deg);
    scan_sum_k<<<NB_SCAN, 256, 0, stream>>>(deg, bsum);
    scan_top_k<<<1, 512, 0, stream>>>(bsum, boff);
    scan_fin_k<<<NB_SCAN, 256, 0, stream>>>(deg, boff, rowptr, cursor);
    fill_part_k<<<NCHUNK * NPART, 256, 0, stream>>>(src, dst, cursor, csr);

    // ---- layer 1 (input dim 2) -> stats[0] ----
    gmlp1_k<<<(NN + 63) / 64, 64, 0, stream>>>(x, rowptr, csr,
                                               w1_in, b1_in, w1_out, b1_out, bufA, stats);

    // ---- layers 2..5 (input dim 32); BN(j) recomputed in-block ----
    const unsigned short* cur = bufA;
    unsigned short* nxt = bufB;
    for (int j = 0; j < 4; j++) {
        gmlp32_k<<<NN / 32, 256, 0, stream>>>(cur, stats + j * 64,
                                              gamma + j * 32, beta + j * 32,
                                              rowptr, csr,
                                              ws_in + j * 1024, bs_in + j * 32,
                                              ws_out + j * 1024, bs_out + j * 32,
                                              nxt, stats + (j + 1) * 64);
        unsigned short* tmp = (unsigned short*)cur; cur = nxt; nxt = tmp;
    }

    // ---- pool (BN(4) in-block) + head ----
    pool_seg_k<<<NG, 256, 0, stream>>>(cur, stats + 4 * 64,
                                       gamma + 4 * 32, beta + 4 * 32, batch, g);
    head_k<<<1, 256, 0, stream>>>(g, fc1w, fc1b, fc2w, fc2b, out);
}